// Round 21
// baseline (202.833 us; speedup 1.0000x reference)
//
#include <hip/hip_runtime.h>
#include <math.h>

// ---------------------------------------------------------------------------
// R-GCN (basis decomposition, B=2), 2 layers.  [r21 = r18 + dense 3x64-col
// W chunks with launch_bounds(512,6): the one untimed lever from r19,
// isolated. Bitwise-identical math to r18's dense.]
//   C[n, 0:192] = x[n,:] @ [loop_w | basis0 | basis1]   (dense, MFMA bf16x3)
//   self = C[:,0:64]+bias ;  hbb[n][j] = pack(bf16 C[n,64+j], bf16 C[n,128+j])
//   out[n] = act(self[n] + sum_{e: dst=n} c0*b0[src][j] + c1*b1[src][j])
//
// Dense via matrix cores with fp32 emulation: x = xh + xl, w = wh + wl
// (bf16 hi/lo, RNE); C = xh*wh + xh*wl + xl*wh  (xl*wl ~ 2^-18, dropped).
// Dense shape: 512 thr / 8 waves, W staged in three 64-col chunks (32KB LDS)
// -> 3 blocks/CU (782/768 = 1.02 residency rounds vs r18's 1.53).
//
// hb stored as PACKED BF16 PAIRS (u32/col): 256B/edge gather (r13).
// Aggregation: v_dot2_f32_bf16 -- 1 VALU op/edge (r16); readlane -> SGPR
// records, saddr gathers (r14). Agg is at its XCD-replication floor
// (126.6MB L2-miss traffic, ~45us) -- closed after 6 structural attempts.
// CSR build fully parallel (r9/r12), wconv+comp-pack fused into count (r14).
// ---------------------------------------------------------------------------

typedef short          short8 __attribute__((ext_vector_type(8)));
typedef float          f32x4  __attribute__((ext_vector_type(4)));
typedef unsigned short u16;

#define NCHUNK 256       // chunk blocks for count/scatter

static __device__ __forceinline__ u16 bf16_rne(float x) {
    unsigned u = __float_as_uint(x);
    return (u16)((u + 0x7fffu + ((u >> 16) & 1u)) >> 16);
}
static __device__ __forceinline__ float bf16_f32(u16 h) {
    return __uint_as_float(((unsigned)h) << 16);
}

// acc += dot2(v as 2xbf16, c as 2xbf16)  -- 1 VALU op (VOP3P, 1 SGPR src ok)
#define DOT2_ACC(acc, vv, cc) \
    asm("v_dot2_f32_bf16 %0, %1, %2, %0" : "+v"(acc) : "v"(vv), "s"(cc))

// ---------------- prep: W pre-convert + comp pack + bucket count -----------
__device__ __forceinline__ void wconv_body(
    int tid,
    const float* __restrict__ loopw1, const float* __restrict__ basis1,
    const float* __restrict__ loopw2, const float* __restrict__ basis2,
    const float* __restrict__ comp1, const float* __restrict__ comp2,
    u16* __restrict__ wt1h, u16* __restrict__ wt1l,
    u16* __restrict__ wt2h, u16* __restrict__ wt2l,
    unsigned* __restrict__ cpk1, unsigned* __restrict__ cpk2)
{
    if (tid < 192 * 128) {                       // layer 1, K=128
        const int j = tid >> 7, k = tid & 127;
        const float w = (j < 64)
            ? loopw1[k * 64 + j]
            : basis1[(size_t)((j - 64) >> 6) * (128 * 64) + k * 64 + ((j - 64) & 63)];
        const u16 h = bf16_rne(w);
        wt1h[tid] = h;
        wt1l[tid] = bf16_rne(w - bf16_f32(h));
    }
    if (tid < 192 * 64) {                        // layer 2, K=64
        const int j = tid >> 6, k = tid & 63;
        const float w = (j < 64)
            ? loopw2[k * 64 + j]
            : basis2[(size_t)((j - 64) >> 6) * (64 * 64) + k * 64 + ((j - 64) & 63)];
        const u16 h = bf16_rne(w);
        wt2h[tid] = h;
        wt2l[tid] = bf16_rne(w - bf16_f32(h));
    }
    if (tid < 50) {                              // comp -> packed bf16 pairs
        cpk1[tid] = (unsigned)bf16_rne(comp1[2 * tid])
                  | ((unsigned)bf16_rne(comp1[2 * tid + 1]) << 16);
        cpk2[tid] = (unsigned)bf16_rne(comp2[2 * tid])
                  | ((unsigned)bf16_rne(comp2[2 * tid + 1]) << 16);
    }
}

__global__ __launch_bounds__(256) void prep_count(
    const int* __restrict__ dst, int* __restrict__ cnt, int nE, int nB,
    const float* __restrict__ loopw1, const float* __restrict__ basis1,
    const float* __restrict__ loopw2, const float* __restrict__ basis2,
    const float* __restrict__ comp1, const float* __restrict__ comp2,
    u16* __restrict__ wt1h, u16* __restrict__ wt1l,
    u16* __restrict__ wt2h, u16* __restrict__ wt2l,
    unsigned* __restrict__ cpk1, unsigned* __restrict__ cpk2)
{
    const int t = threadIdx.x;
    if (blockIdx.x >= NCHUNK) {                  // wconv part
        wconv_body((blockIdx.x - NCHUNK) * 256 + t,
                   loopw1, basis1, loopw2, basis2, comp1, comp2,
                   wt1h, wt1l, wt2h, wt2l, cpk1, cpk2);
        return;
    }
    __shared__ int lh[1024];
    for (int b = t; b < 1024; b += 256) lh[b] = 0;
    __syncthreads();
    const int chunk = (nE + NCHUNK - 1) / NCHUNK;
    const int e0 = blockIdx.x * chunk;
    const int e1 = min(nE, e0 + chunk);
    for (int e = e0 + t; e < e1; e += 256)
        atomicAdd(&lh[dst[e] >> 7], 1);
    __syncthreads();
    for (int b = t; b < nB; b += 256)
        cnt[blockIdx.x * nB + b] = lh[b];        // plain store
}

// ---------------- dense: 128 nodes/block, 8 waves, 3x64-col W chunks -------
template<int K>
__global__ __launch_bounds__(512, 6) void rgcn_dense_mfma(
    const float* __restrict__ x,     // [N][K] f32
    const u16* __restrict__ wth,     // [192][K] bf16 hi (transposed)
    const u16* __restrict__ wtl,     // [192][K] bf16 lo
    const float* __restrict__ bias,  // [64]
    float* __restrict__ self,        // [N][64]  = x@loopw + bias
    unsigned* __restrict__ hbb,      // [N][64]  = pack(bf16 b0, bf16 b1)
    int nNodes)
{
    constexpr int KC  = K / 32;          // mfma K-steps
    constexpr int GW  = K / 8;           // 16B granules per (col,split)
    constexpr int GMW = GW - 1;          // granule XOR mask
    constexpr int TG  = 64 * 2 * GW;     // short8 granules per 64-col chunk
    __shared__ u16 wlds[64 * 2 * K];     // one 64-col chunk (hi+lo): 32/16KB

    const int n0   = blockIdx.x * 128;
    const int lane = threadIdx.x & 63;
    const int w    = threadIdx.x >> 6;   // 0..7
    const int rl   = lane & 15;          // A row / B col / D col
    const int kb   = lane >> 4;          // k-block

    // ---- A fragments: global -> reg, convert to bf16 hi/lo ----
    const int row = n0 + w * 16 + rl;
    short8 Ah[KC], Al[KC];
    #pragma unroll
    for (int kc = 0; kc < KC; ++kc) {
        float v[8];
        if (row < nNodes) {
            const float* xp = x + (size_t)row * K + kc * 32 + kb * 8;
            const float4 a = *reinterpret_cast<const float4*>(xp);
            const float4 b = *reinterpret_cast<const float4*>(xp + 4);
            v[0] = a.x; v[1] = a.y; v[2] = a.z; v[3] = a.w;
            v[4] = b.x; v[5] = b.y; v[6] = b.z; v[7] = b.w;
        } else {
            #pragma unroll
            for (int i = 0; i < 8; ++i) v[i] = 0.f;
        }
        #pragma unroll
        for (int i = 0; i < 8; ++i) {
            const u16 h = bf16_rne(v[i]);
            Ah[kc][i] = (short)h;
            Al[kc][i] = (short)bf16_rne(v[i] - bf16_f32(h));
        }
    }

    f32x4 acc[12];
    #pragma unroll
    for (int j = 0; j < 12; ++j) acc[j] = (f32x4){0.f, 0.f, 0.f, 0.f};

    #pragma unroll
    for (int cc = 0; cc < 3; ++cc) {     // 3 chunks of 64 cols
        if (cc) __syncthreads();         // protect LDS before overwrite
        for (int gi = threadIdx.x; gi < TG; gi += 512) {
            const int ch = gi / (2 * GW);
            const int r2 = gi - ch * 2 * GW;
            const int s  = r2 / GW;
            const int g  = r2 - s * GW;
            const u16* sp = (s == 0 ? wth : wtl)
                          + (size_t)(cc * 64 + ch) * K + g * 8;
            const short8 vv = *reinterpret_cast<const short8*>(sp);
            *reinterpret_cast<short8*>(
                &wlds[((ch * 2 + s) * GW + (g ^ (ch & GMW))) * 8]) = vv;
        }
        __syncthreads();

        #pragma unroll
        for (int j16h = 0; j16h < 4; ++j16h) {
            const int ch = j16h * 16 + rl;
            const u16* bbase = &wlds[(ch * 2) * GW * 8];
            #pragma unroll
            for (int kc = 0; kc < KC; ++kc) {
                const int gp = (kc * 4 + kb) ^ (ch & GMW);
                const short8 Bh =
                    *reinterpret_cast<const short8*>(bbase + gp * 8);
                const short8 Bl =
                    *reinterpret_cast<const short8*>(bbase + (GW + gp) * 8);
                f32x4 a = acc[cc * 4 + j16h];
                a = __builtin_amdgcn_mfma_f32_16x16x32_bf16(Ah[kc], Bh, a, 0, 0, 0);
                a = __builtin_amdgcn_mfma_f32_16x16x32_bf16(Ah[kc], Bl, a, 0, 0, 0);
                a = __builtin_amdgcn_mfma_f32_16x16x32_bf16(Al[kc], Bh, a, 0, 0, 0);
                acc[cc * 4 + j16h] = a;
            }
        }
    }

    // ---- epilogue: D[(kb*4+r)][rl] ----
    // acc[0..3] = cols 0..63 (self); acc[4..7] = cols 64..127 (b0);
    // acc[8..11] = cols 128..191 (b1) -- same mapping as r18.
    const int rowbase = n0 + w * 16 + kb * 4;
    #pragma unroll
    for (int j16 = 0; j16 < 4; ++j16) {          // cols 0..63 -> self + bias
        const float bj = bias[j16 * 16 + rl];
        #pragma unroll
        for (int r = 0; r < 4; ++r) {
            const int rr = rowbase + r;
            if (rr < nNodes)
                self[(size_t)rr * 64 + j16 * 16 + rl] = acc[j16][r] + bj;
        }
    }
    #pragma unroll
    for (int j16 = 4; j16 < 8; ++j16) {          // pack (b0,b1) -> u32
        #pragma unroll
        for (int r = 0; r < 4; ++r) {
            const int rr = rowbase + r;
            if (rr < nNodes)
                hbb[(size_t)rr * 64 + (j16 - 4) * 16 + rl] =
                    (unsigned)bf16_rne(acc[j16][r])
                  | ((unsigned)bf16_rne(acc[j16 + 4][r]) << 16);
        }
    }
}

// ---------------- bucket build (parallel scans) ----------------------------
__global__ __launch_bounds__(NCHUNK) void bkt_chunkscan(
    int* __restrict__ cnt, int* __restrict__ tot, int nB)
{
    __shared__ int sm[NCHUNK];
    const int b = blockIdx.x, t = threadIdx.x;
    const int v = cnt[t * nB + b];
    sm[t] = v;
    __syncthreads();
    for (int off = 1; off < NCHUNK; off <<= 1) {  // Hillis-Steele inclusive
        const int u = (t >= off) ? sm[t - off] : 0;
        __syncthreads();
        sm[t] += u;
        __syncthreads();
    }
    cnt[t * nB + b] = sm[t] - v;                  // exclusive
    if (t == NCHUNK - 1) tot[b] = sm[t];
}

__global__ __launch_bounds__(1024) void bkt_boff(
    const int* __restrict__ tot, int* __restrict__ boff, int nB, int nE)
{
    __shared__ int sm[1024];
    const int t = threadIdx.x;
    const int v = (t < nB) ? tot[t] : 0;
    sm[t] = v; __syncthreads();
    for (int off = 1; off < 1024; off <<= 1) {
        const int u = (t >= off) ? sm[t - off] : 0;
        __syncthreads();
        sm[t] += u;
        __syncthreads();
    }
    if (t < nB) boff[t] = sm[t] - v;              // exclusive
    if (t == 0) boff[nB] = nE;
}

// rec = dl(7)<<23 | src(17)<<6 | et(6); single pass, LDS cursors
__global__ __launch_bounds__(256) void bkt_scatter(
    const int* __restrict__ src, const int* __restrict__ dst,
    const int* __restrict__ et, const int* __restrict__ cnt,
    const int* __restrict__ boff, unsigned* __restrict__ rec,
    int nE, int nB)
{
    __shared__ int lcur[1024];
    const int t = threadIdx.x;
    const int c = blockIdx.x;
    for (int b = t; b < nB; b += 256)
        lcur[b] = boff[b] + cnt[c * nB + b];
    __syncthreads();
    const int chunk = (nE + NCHUNK - 1) / NCHUNK;
    const int e0 = c * chunk;
    const int e1 = min(nE, e0 + chunk);
    for (int e = e0 + t; e < e1; e += 256) {
        const int d = dst[e];
        const int p = atomicAdd(&lcur[d >> 7], 1);
        rec[p] = ((unsigned)(d & 127) << 23)
               | ((unsigned)src[e] << 6)
               | (unsigned)et[e];
    }
}

// ---------------- per-bucket counting sort by node; emits rowptr -----------
__global__ __launch_bounds__(256) void bkt_sort(
    const unsigned* __restrict__ rec, unsigned* __restrict__ rec2,
    const int* __restrict__ boff, int* __restrict__ rowptr,
    int nNodes)
{
    __shared__ int cnt[128];
    __shared__ int pos[128];
    const int b = blockIdx.x;
    const int t = threadIdx.x;
    const int beg = boff[b], end = boff[b + 1];
    if (t < 128) cnt[t] = 0;
    __syncthreads();
    for (int i = beg + t; i < end; i += 256)
        atomicAdd(&cnt[rec[i] >> 23], 1);
    __syncthreads();
    if (t < 128) pos[t] = cnt[t];
    __syncthreads();
    for (int off = 1; off < 128; off <<= 1) {     // Hillis-Steele inclusive
        int u = 0;
        if (t < 128 && t >= off) u = pos[t - off];
        __syncthreads();
        if (t < 128) pos[t] += u;
        __syncthreads();
    }
    if (t < 128) {
        const int ex = beg + pos[t] - cnt[t];     // exclusive + bucket base
        pos[t] = ex;
        const int n = (b << 7) + t;
        if (n < nNodes) rowptr[n] = ex;
    }
    __syncthreads();
    for (int i = beg + t; i < end; i += 256) {
        const unsigned r = rec[i];
        const int p = atomicAdd(&pos[r >> 23], 1);
        rec2[p] = r;                               // bucket-window write
    }
}

// ---------------- edge aggregation: one wave per node, dot2 math -----------
template<int ACT>   // 0 = tanh, 1 = relu
__global__ __launch_bounds__(256) void rgcn_agg(
    const unsigned* __restrict__ hbb,   // [N][64] u32 = (bf16 b0, bf16 b1)
    const unsigned* __restrict__ cpk,   // [R] u32 = (bf16 c0, bf16 c1)
    const int* __restrict__ rowptr,     // [N], node-sorted rec2 offsets
    const unsigned* __restrict__ rec2,  // [E] node-grouped
    float* __restrict__ io,             // in: self+bias, out: act(self+agg)
    int nNodes, int nEdges)
{
    const int lane = threadIdx.x & 63;
    const int w  = (blockIdx.x * 256 + threadIdx.x) >> 6;
    const int nW = (gridDim.x * 256) >> 6;
    for (int n = w; n < nNodes; n += nW) {
        const int beg = rowptr[n];
        const int end = (n == nNodes - 1) ? nEdges : rowptr[n + 1];
        const float self = io[(size_t)n * 64 + lane];   // issue early
        float acc0 = 0.f, acc1 = 0.f;
        for (int base = beg; base < end; base += 64) {
            const int cnt = min(64, end - base);
            const unsigned r = (lane < cnt) ? rec2[base + lane] : 0u;
            int i = 0;
            for (; i + 8 <= cnt; i += 8) {        // 8 saddr gathers in flight
                int ss[8]; unsigned cp[8];
                #pragma unroll
                for (int k = 0; k < 8; ++k) {
                    const unsigned rk =
                        (unsigned)__builtin_amdgcn_readlane((int)r, i + k);
                    ss[k] = (int)((rk >> 6) & 0x1FFFFu);
                    cp[k] = cpk[rk & 63u];        // uniform -> s_load
                }
                unsigned v[8];
                #pragma unroll
                for (int k = 0; k < 8; ++k)
                    v[k] = hbb[(size_t)ss[k] * 64 + lane];
                #pragma unroll
                for (int k = 0; k < 8; ++k) {
                    if (k & 1) { DOT2_ACC(acc1, v[k], cp[k]); }
                    else       { DOT2_ACC(acc0, v[k], cp[k]); }
                }
            }
            for (; i + 2 <= cnt; i += 2) {        // pair tail
                const unsigned rA =
                    (unsigned)__builtin_amdgcn_readlane((int)r, i);
                const unsigned rB =
                    (unsigned)__builtin_amdgcn_readlane((int)r, i + 1);
                const unsigned cA = cpk[rA & 63u], cB = cpk[rB & 63u];
                const unsigned vA = hbb[(size_t)((rA >> 6) & 0x1FFFFu) * 64 + lane];
                const unsigned vB = hbb[(size_t)((rB >> 6) & 0x1FFFFu) * 64 + lane];
                DOT2_ACC(acc0, vA, cA);
                DOT2_ACC(acc1, vB, cB);
            }
            if (i < cnt) {                        // single tail
                const unsigned rA =
                    (unsigned)__builtin_amdgcn_readlane((int)r, i);
                const unsigned cA = cpk[rA & 63u];
                const unsigned vA = hbb[(size_t)((rA >> 6) & 0x1FFFFu) * 64 + lane];
                DOT2_ACC(acc0, vA, cA);
            }
        }
        float o = self + acc0 + acc1;
        o = (ACT == 0) ? tanhf(o) : fmaxf(o, 0.f);
        io[(size_t)n * 64 + lane] = o;
    }
}

// ---------------------------------------------------------------------------
extern "C" void kernel_launch(void* const* d_in, const int* in_sizes, int n_in,
                              void* d_out, int out_size, void* d_ws, size_t ws_size,
                              hipStream_t stream)
{
    const float* node_emb = (const float*)d_in[0];   // [N][128]
    const float* basis1   = (const float*)d_in[1];   // [2][128][64]
    const float* comp1    = (const float*)d_in[2];   // [R][2]
    const float* loop_w1  = (const float*)d_in[3];   // [128][64]
    const float* bias1    = (const float*)d_in[4];   // [64]
    const float* basis2   = (const float*)d_in[5];   // [2][64][64]
    const float* comp2    = (const float*)d_in[6];   // [R][2]
    const float* loop_w2  = (const float*)d_in[7];   // [64][64]
    const float* bias2    = (const float*)d_in[8];   // [64]
    const int*   src      = (const int*)d_in[9];     // [E]
    const int*   dst      = (const int*)d_in[10];    // [E]
    const int*   et       = (const int*)d_in[11];    // [E]

    const int N = in_sizes[0] / 128;
    const int E = in_sizes[9];
    const int nB = (N + 127) / 128;                  // dst buckets (<=1024)

    float* out = (float*)d_out;                      // [N][64]

    // workspace layout
    unsigned* hbb    = (unsigned*)d_ws;              // N*64 u32 (packed pairs)
    float*    h      = (float*)(hbb + (size_t)N * 64); // N*64 f
    unsigned* rec    = (unsigned*)(h + (size_t)N * 64); // E u32 (bucket-grouped)
    unsigned* rec2   = rec + E;                      // E u32 (node-grouped)
    int*      cnt    = (int*)(rec2 + E);             // NCHUNK*nB
    int*      tot    = cnt + NCHUNK * nB;            // nB
    int*      boff   = tot + nB;                     // nB+1
    int*      rowptr = boff + nB + 1;                // N
    u16*      wt1h   = (u16*)(rowptr + N);           // 192*128
    u16*      wt1l   = wt1h + 192 * 128;
    u16*      wt2h   = wt1l + 192 * 128;             // 192*64
    u16*      wt2l   = wt2h + 192 * 64;
    unsigned* cpk1   = (unsigned*)(wt2l + 192 * 64); // 64 u32
    unsigned* cpk2   = cpk1 + 64;

    const int nBlkDense = (N + 127) / 128;
    const int nBlkAgg   = (N + 3) / 4;               // 1 wave per node

    // ---- prep: wconv + comp pack + bucket count (fused) ----
    prep_count<<<NCHUNK + 96, 256, 0, stream>>>(
        dst, cnt, E, nB, loop_w1, basis1, loop_w2, basis2, comp1, comp2,
        wt1h, wt1l, wt2h, wt2l, cpk1, cpk2);

    // ---- per-node CSR: chunkscan -> boff -> scatter -> sort ----
    bkt_chunkscan<<<nB, NCHUNK, 0, stream>>>(cnt, tot, nB);
    bkt_boff     <<<1,    1024, 0, stream>>>(tot, boff, nB, E);
    bkt_scatter  <<<NCHUNK, 256, 0, stream>>>(src, dst, et, cnt, boff, rec, E, nB);
    bkt_sort     <<<nB,     256, 0, stream>>>(rec, rec2, boff, rowptr, N);

    // ---- layer 1 ----
    rgcn_dense_mfma<128><<<nBlkDense, 512, 0, stream>>>(
        node_emb, wt1h, wt1l, bias1, h, hbb, N);
    rgcn_agg<0><<<nBlkAgg, 256, 0, stream>>>(
        hbb, cpk1, rowptr, rec2, h, N, E);

    // ---- layer 2 ----
    rgcn_dense_mfma<64><<<nBlkDense, 512, 0, stream>>>(
        h, wt2h, wt2l, bias2, out, hbb, N);
    rgcn_agg<1><<<nBlkAgg, 256, 0, stream>>>(
        hbb, cpk2, rowptr, rec2, out, N, E);
}

// Round 22
// 188.519 us; speedup vs baseline: 1.0759x; 1.0759x over previous
//
#include <hip/hip_runtime.h>
#include <math.h>

// ---------------------------------------------------------------------------
// R-GCN (basis decomposition, B=2), 2 layers.  [FINAL = r18: proven-best,
// 188.5us, absmax 2.44e-4. r21's 3-chunk dense regressed (+13us) -> reverted.]
//   C[n, 0:192] = x[n,:] @ [loop_w | basis0 | basis1]   (dense, MFMA bf16x3)
//   self = C[:,0:64]+bias ;  hbb[n][j] = pack(bf16 C[n,64+j], bf16 C[n,128+j])
//   out[n] = act(self[n] + sum_{e: dst=n} c0*b0[src][j] + c1*b1[src][j])
//
// Dense via matrix cores with fp32 emulation: x = xh + xl, w = wh + wl
// (bf16 hi/lo, RNE); C = xh*wh + xh*wl + xl*wh  (xl*wl ~ 2^-18, dropped).
// Dense shape: 512 thr / 8 waves, W staged in two 96-col halves per block
// (r14-proven; 5 restructures all neutral/regressed -- closed).
//
// hb stored as PACKED BF16 PAIRS (u32/col): 256B/edge gather (r13).
// Aggregation: v_dot2_f32_bf16 -- 1 VALU op/edge (r16); readlane -> SGPR
// records, saddr gathers (r14). Agg pinned at XCD-L2-replication fetch floor
// (126.6MB, ~45us) across 7 structural attempts -- closed.
// CSR build fully parallel (r9/r12), wconv+comp-pack fused into count (r14).
// ---------------------------------------------------------------------------

typedef short          short8 __attribute__((ext_vector_type(8)));
typedef float          f32x4  __attribute__((ext_vector_type(4)));
typedef unsigned short u16;

#define NCHUNK 256       // chunk blocks for count/scatter

static __device__ __forceinline__ u16 bf16_rne(float x) {
    unsigned u = __float_as_uint(x);
    return (u16)((u + 0x7fffu + ((u >> 16) & 1u)) >> 16);
}
static __device__ __forceinline__ float bf16_f32(u16 h) {
    return __uint_as_float(((unsigned)h) << 16);
}

// acc += dot2(v as 2xbf16, c as 2xbf16)  -- 1 VALU op (VOP3P, 1 SGPR src ok)
#define DOT2_ACC(acc, vv, cc) \
    asm("v_dot2_f32_bf16 %0, %1, %2, %0" : "+v"(acc) : "v"(vv), "s"(cc))

// ---------------- prep: W pre-convert + comp pack + bucket count -----------
__device__ __forceinline__ void wconv_body(
    int tid,
    const float* __restrict__ loopw1, const float* __restrict__ basis1,
    const float* __restrict__ loopw2, const float* __restrict__ basis2,
    const float* __restrict__ comp1, const float* __restrict__ comp2,
    u16* __restrict__ wt1h, u16* __restrict__ wt1l,
    u16* __restrict__ wt2h, u16* __restrict__ wt2l,
    unsigned* __restrict__ cpk1, unsigned* __restrict__ cpk2)
{
    if (tid < 192 * 128) {                       // layer 1, K=128
        const int j = tid >> 7, k = tid & 127;
        const float w = (j < 64)
            ? loopw1[k * 64 + j]
            : basis1[(size_t)((j - 64) >> 6) * (128 * 64) + k * 64 + ((j - 64) & 63)];
        const u16 h = bf16_rne(w);
        wt1h[tid] = h;
        wt1l[tid] = bf16_rne(w - bf16_f32(h));
    }
    if (tid < 192 * 64) {                        // layer 2, K=64
        const int j = tid >> 6, k = tid & 63;
        const float w = (j < 64)
            ? loopw2[k * 64 + j]
            : basis2[(size_t)((j - 64) >> 6) * (64 * 64) + k * 64 + ((j - 64) & 63)];
        const u16 h = bf16_rne(w);
        wt2h[tid] = h;
        wt2l[tid] = bf16_rne(w - bf16_f32(h));
    }
    if (tid < 50) {                              // comp -> packed bf16 pairs
        cpk1[tid] = (unsigned)bf16_rne(comp1[2 * tid])
                  | ((unsigned)bf16_rne(comp1[2 * tid + 1]) << 16);
        cpk2[tid] = (unsigned)bf16_rne(comp2[2 * tid])
                  | ((unsigned)bf16_rne(comp2[2 * tid + 1]) << 16);
    }
}

__global__ __launch_bounds__(256) void prep_count(
    const int* __restrict__ dst, int* __restrict__ cnt, int nE, int nB,
    const float* __restrict__ loopw1, const float* __restrict__ basis1,
    const float* __restrict__ loopw2, const float* __restrict__ basis2,
    const float* __restrict__ comp1, const float* __restrict__ comp2,
    u16* __restrict__ wt1h, u16* __restrict__ wt1l,
    u16* __restrict__ wt2h, u16* __restrict__ wt2l,
    unsigned* __restrict__ cpk1, unsigned* __restrict__ cpk2)
{
    const int t = threadIdx.x;
    if (blockIdx.x >= NCHUNK) {                  // wconv part
        wconv_body((blockIdx.x - NCHUNK) * 256 + t,
                   loopw1, basis1, loopw2, basis2, comp1, comp2,
                   wt1h, wt1l, wt2h, wt2l, cpk1, cpk2);
        return;
    }
    __shared__ int lh[1024];
    for (int b = t; b < 1024; b += 256) lh[b] = 0;
    __syncthreads();
    const int chunk = (nE + NCHUNK - 1) / NCHUNK;
    const int e0 = blockIdx.x * chunk;
    const int e1 = min(nE, e0 + chunk);
    for (int e = e0 + t; e < e1; e += 256)
        atomicAdd(&lh[dst[e] >> 7], 1);
    __syncthreads();
    for (int b = t; b < nB; b += 256)
        cnt[blockIdx.x * nB + b] = lh[b];        // plain store
}

// ---------------- dense: 128 nodes/block, 8 waves, W in LDS (r14 shape) ----
template<int K>
__global__ __launch_bounds__(512, 2) void rgcn_dense_mfma(
    const float* __restrict__ x,     // [N][K] f32
    const u16* __restrict__ wth,     // [192][K] bf16 hi (transposed)
    const u16* __restrict__ wtl,     // [192][K] bf16 lo
    const float* __restrict__ bias,  // [64]
    float* __restrict__ self,        // [N][64]  = x@loopw + bias
    unsigned* __restrict__ hbb,      // [N][64]  = pack(bf16 b0, bf16 b1)
    int nNodes)
{
    constexpr int KC  = K / 32;          // mfma K-steps
    constexpr int GW  = K / 8;           // 16B granules per (col,split)
    constexpr int GMW = GW - 1;          // granule XOR mask
    __shared__ u16 wlds[96 * 2 * K];     // one 96-col half of W (hi+lo)

    const int n0   = blockIdx.x * 128;
    const int lane = threadIdx.x & 63;
    const int w    = threadIdx.x >> 6;   // 0..7
    const int rl   = lane & 15;          // A row / B col / D col
    const int kb   = lane >> 4;          // k-block

    // ---- A fragments: global -> reg, convert to bf16 hi/lo ----
    const int row = n0 + w * 16 + rl;
    short8 Ah[KC], Al[KC];
    #pragma unroll
    for (int kc = 0; kc < KC; ++kc) {
        float v[8];
        if (row < nNodes) {
            const float* xp = x + (size_t)row * K + kc * 32 + kb * 8;
            const float4 a = *reinterpret_cast<const float4*>(xp);
            const float4 b = *reinterpret_cast<const float4*>(xp + 4);
            v[0] = a.x; v[1] = a.y; v[2] = a.z; v[3] = a.w;
            v[4] = b.x; v[5] = b.y; v[6] = b.z; v[7] = b.w;
        } else {
            #pragma unroll
            for (int i = 0; i < 8; ++i) v[i] = 0.f;
        }
        #pragma unroll
        for (int i = 0; i < 8; ++i) {
            const u16 h = bf16_rne(v[i]);
            Ah[kc][i] = (short)h;
            Al[kc][i] = (short)bf16_rne(v[i] - bf16_f32(h));
        }
    }

    f32x4 acc[12];
    #pragma unroll
    for (int j = 0; j < 12; ++j) acc[j] = (f32x4){0.f, 0.f, 0.f, 0.f};

    #pragma unroll
    for (int hf = 0; hf < 2; ++hf) {
        if (hf) __syncthreads();         // protect LDS before overwrite
        // ---- stage 96 cols of W (hi+lo) into LDS, XOR-swizzled ----
        for (int gi = threadIdx.x; gi < 96 * 2 * GW; gi += 512) {
            const int ch = gi / (2 * GW);
            const int r  = gi - ch * 2 * GW;
            const int s  = r / GW;
            const int g  = r - s * GW;
            const u16* sp = (s == 0 ? wth : wtl)
                          + (size_t)(hf * 96 + ch) * K + g * 8;
            const short8 vv = *reinterpret_cast<const short8*>(sp);
            *reinterpret_cast<short8*>(
                &wlds[((ch * 2 + s) * GW + (g ^ (ch & GMW))) * 8]) = vv;
        }
        __syncthreads();

        #pragma unroll
        for (int j16h = 0; j16h < 6; ++j16h) {
            const int ch = j16h * 16 + rl;
            const u16* bbase = &wlds[(ch * 2) * GW * 8];
            #pragma unroll
            for (int kc = 0; kc < KC; ++kc) {
                const int gp = (kc * 4 + kb) ^ (ch & GMW);
                const short8 Bh =
                    *reinterpret_cast<const short8*>(bbase + gp * 8);
                const short8 Bl =
                    *reinterpret_cast<const short8*>(bbase + (GW + gp) * 8);
                f32x4 a = acc[hf * 6 + j16h];
                a = __builtin_amdgcn_mfma_f32_16x16x32_bf16(Ah[kc], Bh, a, 0, 0, 0);
                a = __builtin_amdgcn_mfma_f32_16x16x32_bf16(Ah[kc], Bl, a, 0, 0, 0);
                a = __builtin_amdgcn_mfma_f32_16x16x32_bf16(Al[kc], Bh, a, 0, 0, 0);
                acc[hf * 6 + j16h] = a;
            }
        }
    }

    // ---- epilogue: D[(kb*4+r)][rl] ----
    const int rowbase = n0 + w * 16 + kb * 4;
    #pragma unroll
    for (int j16 = 0; j16 < 4; ++j16) {          // cols 0..63 -> self + bias
        const float bj = bias[j16 * 16 + rl];
        #pragma unroll
        for (int r = 0; r < 4; ++r) {
            const int rr = rowbase + r;
            if (rr < nNodes)
                self[(size_t)rr * 64 + j16 * 16 + rl] = acc[j16][r] + bj;
        }
    }
    #pragma unroll
    for (int j16 = 4; j16 < 8; ++j16) {          // pack (b0,b1) -> u32
        #pragma unroll
        for (int r = 0; r < 4; ++r) {
            const int rr = rowbase + r;
            if (rr < nNodes)
                hbb[(size_t)rr * 64 + (j16 - 4) * 16 + rl] =
                    (unsigned)bf16_rne(acc[j16][r])
                  | ((unsigned)bf16_rne(acc[j16 + 4][r]) << 16);
        }
    }
}

// ---------------- bucket build (parallel scans) ----------------------------
__global__ __launch_bounds__(NCHUNK) void bkt_chunkscan(
    int* __restrict__ cnt, int* __restrict__ tot, int nB)
{
    __shared__ int sm[NCHUNK];
    const int b = blockIdx.x, t = threadIdx.x;
    const int v = cnt[t * nB + b];
    sm[t] = v;
    __syncthreads();
    for (int off = 1; off < NCHUNK; off <<= 1) {  // Hillis-Steele inclusive
        const int u = (t >= off) ? sm[t - off] : 0;
        __syncthreads();
        sm[t] += u;
        __syncthreads();
    }
    cnt[t * nB + b] = sm[t] - v;                  // exclusive
    if (t == NCHUNK - 1) tot[b] = sm[t];
}

__global__ __launch_bounds__(1024) void bkt_boff(
    const int* __restrict__ tot, int* __restrict__ boff, int nB, int nE)
{
    __shared__ int sm[1024];
    const int t = threadIdx.x;
    const int v = (t < nB) ? tot[t] : 0;
    sm[t] = v; __syncthreads();
    for (int off = 1; off < 1024; off <<= 1) {
        const int u = (t >= off) ? sm[t - off] : 0;
        __syncthreads();
        sm[t] += u;
        __syncthreads();
    }
    if (t < nB) boff[t] = sm[t] - v;              // exclusive
    if (t == 0) boff[nB] = nE;
}

// rec = dl(7)<<23 | src(17)<<6 | et(6); single pass, LDS cursors
__global__ __launch_bounds__(256) void bkt_scatter(
    const int* __restrict__ src, const int* __restrict__ dst,
    const int* __restrict__ et, const int* __restrict__ cnt,
    const int* __restrict__ boff, unsigned* __restrict__ rec,
    int nE, int nB)
{
    __shared__ int lcur[1024];
    const int t = threadIdx.x;
    const int c = blockIdx.x;
    for (int b = t; b < nB; b += 256)
        lcur[b] = boff[b] + cnt[c * nB + b];
    __syncthreads();
    const int chunk = (nE + NCHUNK - 1) / NCHUNK;
    const int e0 = c * chunk;
    const int e1 = min(nE, e0 + chunk);
    for (int e = e0 + t; e < e1; e += 256) {
        const int d = dst[e];
        const int p = atomicAdd(&lcur[d >> 7], 1);
        rec[p] = ((unsigned)(d & 127) << 23)
               | ((unsigned)src[e] << 6)
               | (unsigned)et[e];
    }
}

// ---------------- per-bucket counting sort by node; emits rowptr -----------
__global__ __launch_bounds__(256) void bkt_sort(
    const unsigned* __restrict__ rec, unsigned* __restrict__ rec2,
    const int* __restrict__ boff, int* __restrict__ rowptr,
    int nNodes)
{
    __shared__ int cnt[128];
    __shared__ int pos[128];
    const int b = blockIdx.x;
    const int t = threadIdx.x;
    const int beg = boff[b], end = boff[b + 1];
    if (t < 128) cnt[t] = 0;
    __syncthreads();
    for (int i = beg + t; i < end; i += 256)
        atomicAdd(&cnt[rec[i] >> 23], 1);
    __syncthreads();
    if (t < 128) pos[t] = cnt[t];
    __syncthreads();
    for (int off = 1; off < 128; off <<= 1) {     // Hillis-Steele inclusive
        int u = 0;
        if (t < 128 && t >= off) u = pos[t - off];
        __syncthreads();
        if (t < 128) pos[t] += u;
        __syncthreads();
    }
    if (t < 128) {
        const int ex = beg + pos[t] - cnt[t];     // exclusive + bucket base
        pos[t] = ex;
        const int n = (b << 7) + t;
        if (n < nNodes) rowptr[n] = ex;
    }
    __syncthreads();
    for (int i = beg + t; i < end; i += 256) {
        const unsigned r = rec[i];
        const int p = atomicAdd(&pos[r >> 23], 1);
        rec2[p] = r;                               // bucket-window write
    }
}

// ---------------- edge aggregation: one wave per node, dot2 math -----------
template<int ACT>   // 0 = tanh, 1 = relu
__global__ __launch_bounds__(256) void rgcn_agg(
    const unsigned* __restrict__ hbb,   // [N][64] u32 = (bf16 b0, bf16 b1)
    const unsigned* __restrict__ cpk,   // [R] u32 = (bf16 c0, bf16 c1)
    const int* __restrict__ rowptr,     // [N], node-sorted rec2 offsets
    const unsigned* __restrict__ rec2,  // [E] node-grouped
    float* __restrict__ io,             // in: self+bias, out: act(self+agg)
    int nNodes, int nEdges)
{
    const int lane = threadIdx.x & 63;
    const int w  = (blockIdx.x * 256 + threadIdx.x) >> 6;
    const int nW = (gridDim.x * 256) >> 6;
    for (int n = w; n < nNodes; n += nW) {
        const int beg = rowptr[n];
        const int end = (n == nNodes - 1) ? nEdges : rowptr[n + 1];
        const float self = io[(size_t)n * 64 + lane];   // issue early
        float acc0 = 0.f, acc1 = 0.f;
        for (int base = beg; base < end; base += 64) {
            const int cnt = min(64, end - base);
            const unsigned r = (lane < cnt) ? rec2[base + lane] : 0u;
            int i = 0;
            for (; i + 8 <= cnt; i += 8) {        // 8 saddr gathers in flight
                int ss[8]; unsigned cp[8];
                #pragma unroll
                for (int k = 0; k < 8; ++k) {
                    const unsigned rk =
                        (unsigned)__builtin_amdgcn_readlane((int)r, i + k);
                    ss[k] = (int)((rk >> 6) & 0x1FFFFu);
                    cp[k] = cpk[rk & 63u];        // uniform -> s_load
                }
                unsigned v[8];
                #pragma unroll
                for (int k = 0; k < 8; ++k)
                    v[k] = hbb[(size_t)ss[k] * 64 + lane];
                #pragma unroll
                for (int k = 0; k < 8; ++k) {
                    if (k & 1) { DOT2_ACC(acc1, v[k], cp[k]); }
                    else       { DOT2_ACC(acc0, v[k], cp[k]); }
                }
            }
            for (; i + 2 <= cnt; i += 2) {        // pair tail
                const unsigned rA =
                    (unsigned)__builtin_amdgcn_readlane((int)r, i);
                const unsigned rB =
                    (unsigned)__builtin_amdgcn_readlane((int)r, i + 1);
                const unsigned cA = cpk[rA & 63u], cB = cpk[rB & 63u];
                const unsigned vA = hbb[(size_t)((rA >> 6) & 0x1FFFFu) * 64 + lane];
                const unsigned vB = hbb[(size_t)((rB >> 6) & 0x1FFFFu) * 64 + lane];
                DOT2_ACC(acc0, vA, cA);
                DOT2_ACC(acc1, vB, cB);
            }
            if (i < cnt) {                        // single tail
                const unsigned rA =
                    (unsigned)__builtin_amdgcn_readlane((int)r, i);
                const unsigned cA = cpk[rA & 63u];
                const unsigned vA = hbb[(size_t)((rA >> 6) & 0x1FFFFu) * 64 + lane];
                DOT2_ACC(acc0, vA, cA);
            }
        }
        float o = self + acc0 + acc1;
        o = (ACT == 0) ? tanhf(o) : fmaxf(o, 0.f);
        io[(size_t)n * 64 + lane] = o;
    }
}

// ---------------------------------------------------------------------------
extern "C" void kernel_launch(void* const* d_in, const int* in_sizes, int n_in,
                              void* d_out, int out_size, void* d_ws, size_t ws_size,
                              hipStream_t stream)
{
    const float* node_emb = (const float*)d_in[0];   // [N][128]
    const float* basis1   = (const float*)d_in[1];   // [2][128][64]
    const float* comp1    = (const float*)d_in[2];   // [R][2]
    const float* loop_w1  = (const float*)d_in[3];   // [128][64]
    const float* bias1    = (const float*)d_in[4];   // [64]
    const float* basis2   = (const float*)d_in[5];   // [2][64][64]
    const float* comp2    = (const float*)d_in[6];   // [R][2]
    const float* loop_w2  = (const float*)d_in[7];   // [64][64]
    const float* bias2    = (const float*)d_in[8];   // [64]
    const int*   src      = (const int*)d_in[9];     // [E]
    const int*   dst      = (const int*)d_in[10];    // [E]
    const int*   et       = (const int*)d_in[11];    // [E]

    const int N = in_sizes[0] / 128;
    const int E = in_sizes[9];
    const int nB = (N + 127) / 128;                  // dst buckets (<=1024)

    float* out = (float*)d_out;                      // [N][64]

    // workspace layout
    unsigned* hbb    = (unsigned*)d_ws;              // N*64 u32 (packed pairs)
    float*    h      = (float*)(hbb + (size_t)N * 64); // N*64 f
    unsigned* rec    = (unsigned*)(h + (size_t)N * 64); // E u32 (bucket-grouped)
    unsigned* rec2   = rec + E;                      // E u32 (node-grouped)
    int*      cnt    = (int*)(rec2 + E);             // NCHUNK*nB
    int*      tot    = cnt + NCHUNK * nB;            // nB
    int*      boff   = tot + nB;                     // nB+1
    int*      rowptr = boff + nB + 1;                // N
    u16*      wt1h   = (u16*)(rowptr + N);           // 192*128
    u16*      wt1l   = wt1h + 192 * 128;
    u16*      wt2h   = wt1l + 192 * 128;             // 192*64
    u16*      wt2l   = wt2h + 192 * 64;
    unsigned* cpk1   = (unsigned*)(wt2l + 192 * 64); // 64 u32
    unsigned* cpk2   = cpk1 + 64;

    const int nBlkDense = (N + 127) / 128;
    const int nBlkAgg   = (N + 3) / 4;               // 1 wave per node

    // ---- prep: wconv + comp pack + bucket count (fused) ----
    prep_count<<<NCHUNK + 96, 256, 0, stream>>>(
        dst, cnt, E, nB, loop_w1, basis1, loop_w2, basis2, comp1, comp2,
        wt1h, wt1l, wt2h, wt2l, cpk1, cpk2);

    // ---- per-node CSR: chunkscan -> boff -> scatter -> sort ----
    bkt_chunkscan<<<nB, NCHUNK, 0, stream>>>(cnt, tot, nB);
    bkt_boff     <<<1,    1024, 0, stream>>>(tot, boff, nB, E);
    bkt_scatter  <<<NCHUNK, 256, 0, stream>>>(src, dst, et, cnt, boff, rec, E, nB);
    bkt_sort     <<<nB,     256, 0, stream>>>(rec, rec2, boff, rowptr, N);

    // ---- layer 1 ----
    rgcn_dense_mfma<128><<<nBlkDense, 512, 0, stream>>>(
        node_emb, wt1h, wt1l, bias1, h, hbb, N);
    rgcn_agg<0><<<nBlkAgg, 256, 0, stream>>>(
        hbb, cpk1, rowptr, rec2, h, N, E);

    // ---- layer 2 ----
    rgcn_dense_mfma<64><<<nBlkDense, 512, 0, stream>>>(
        h, wt2h, wt2l, bias2, out, hbb, N);
    rgcn_agg<1><<<nBlkAgg, 256, 0, stream>>>(
        hbb, cpk2, rowptr, rec2, out, N, E);
}